// Round 13
// baseline (146.250 us; speedup 1.0000x reference)
//
#include <hip/hip_runtime.h>

#define NB      16
#define T_IN    2048
#define OUT_LEN 4096
#define D       384
#define D4      (D / 4)     // 96 float4 per row
#define RPB     32          // output rows per block
#define CHUNKS  (RPB * D4 / 256)   // 12 chunks of 256 float4

typedef float f32x4 __attribute__((ext_vector_type(4)));

// ---------------------------------------------------------------------------
// Single fused kernel. Each block owns 32 output rows of one batch
// (2048 blocks = 8 resident blocks x 256 CUs, one full dispatch wave).
//  Phase 1: block recomputes the batch's cumsum (2048 int32, 8 KB L2-resident)
//           into LDS: thread-local scan of 8 + wave shfl scan + cross-wave
//           combine. Amortized over 4x more gather work than the 8-row/block
//           version (phase-1 was ~50% of kernel time there).
//  Phase 2: threads 0..31 binary-search LDS cumsum for their row's input
//           index (-1 when t >= seq_len).
//  Phase 3: 256 threads gather 32 rows x 96 float4 (12 coalesced chunks),
//           zeros for invalid rows (covers the 0xAA poison).
// seq_len (output 1, as float) is written by the first block of each batch.
// ---------------------------------------------------------------------------
__global__ __launch_bounds__(256) void lenreg_kernel(const f32x4* __restrict__ x,
                                                     const int* __restrict__ r,
                                                     f32x4* __restrict__ out,
                                                     float* __restrict__ seqlen_out) {
    __shared__ int scum[T_IN];   // 8 KB
    __shared__ int wsum[4];
    __shared__ int sidx[RPB];

    const unsigned row0 = blockIdx.x * (unsigned)RPB;  // first output row
    const unsigned b    = row0 >> 12;                  // row0 / OUT_LEN
    const int tid = threadIdx.x;

    // ---- Phase 1: per-block cumsum into LDS ----
    const int4* rb = (const int4*)(r + b * T_IN);
    int4 v0 = rb[tid * 2];
    int4 v1 = rb[tid * 2 + 1];
    int v[8] = {v0.x, v0.y, v0.z, v0.w, v1.x, v1.y, v1.z, v1.w};

    int s = 0;
#pragma unroll
    for (int i = 0; i < 8; ++i) { s += v[i]; v[i] = s; }

    const int lane = tid & 63;
    const int wid  = tid >> 6;
    int pre = s;
#pragma unroll
    for (int off = 1; off < 64; off <<= 1) {
        int up = __shfl_up(pre, off, 64);
        if (lane >= off) pre += up;
    }
    if (lane == 63) wsum[wid] = pre;
    __syncthreads();

    int excl = pre - s;                        // exclusive prefix within wave
    for (int w = 0; w < wid; ++w) excl += wsum[w];
#pragma unroll
    for (int i = 0; i < 8; ++i) v[i] += excl;

    ((int4*)scum)[tid * 2]     = make_int4(v[0], v[1], v[2], v[3]);
    ((int4*)scum)[tid * 2 + 1] = make_int4(v[4], v[5], v[6], v[7]);
    __syncthreads();

    // ---- Phase 2: binary search for this block's 32 rows ----
    const int seq = scum[T_IN - 1];            // broadcast read
    if (tid < RPB) {
        const int t = (int)(row0 & (OUT_LEN - 1)) + tid;
        int res = -1;
        if (t < seq) {
            int lo = 0, hi = T_IN;
            while (lo < hi) {
                int mid = (lo + hi) >> 1;
                if (scum[mid] <= t) lo = mid + 1; else hi = mid;
            }
            res = lo < (T_IN - 1) ? lo : (T_IN - 1);
        }
        sidx[tid] = res;
    }
    if (tid == 0 && (row0 & (OUT_LEN - 1)) == 0)
        seqlen_out[b] = (float)seq;            // output 1 (float)
    __syncthreads();

    // ---- Phase 3: gather 32 rows x 96 float4, coalesced ----
    const f32x4*  xb   = x + (size_t)b * T_IN * D4;
    const unsigned base = row0 * (unsigned)D4;

#pragma unroll
    for (int k = 0; k < CHUNKS; ++k) {
        const unsigned local = (unsigned)tid + k * 256u;  // 0..3071
        const unsigned rloc  = local / D4;                // const-96 divide
        const unsigned d     = local - rloc * D4;
        const int irow = sidx[rloc];
        f32x4 val = (f32x4)(0.f);
        if (irow >= 0) val = xb[(unsigned)irow * D4 + d];
        out[base + local] = val;
    }
}

extern "C" void kernel_launch(void* const* d_in, const int* in_sizes, int n_in,
                              void* d_out, int out_size, void* d_ws, size_t ws_size,
                              hipStream_t stream) {
    const float* x  = (const float*)d_in[0];
    const int*   rc = (const int*)d_in[1];
    // d_in[2] = output_max_seq_len scalar (4096), compiled in.

    float* out        = (float*)d_out;
    float* seqlen_out = out + (size_t)NB * OUT_LEN * D;  // tail: output 1

    const unsigned n_rows = (unsigned)NB * OUT_LEN;      // 65536 rows
    lenreg_kernel<<<n_rows / RPB, 256, 0, stream>>>((const f32x4*)x, rc,
                                                    (f32x4*)out, seqlen_out);
}